// Round 10
// baseline (170.819 us; speedup 1.0000x reference)
//
#include <hip/hip_runtime.h>
#include <math.h>

#define NB 4
#define NH 512
#define NW 512
#define NC 19
#define NPIX (NB*NH*NW)
#define TS 16
#define NLAD 128
#define INF6 1.0e6f
#define MAXDIS 1.0e5f
#define NWRD 16          // 512 rows / 32 bits
#define NREP 8           // histogram replicas
#define HSTRIDE 132      // padded per-replica stride (129 bins)
#define NSEG 128         // compaction segments
#define SEGCAP 512       // entries per segment (expected max ~250)
#define R4 4             // rows per klse block
#define NZERO (NREP*HSTRIDE + NSEG)   // hist + cnts words zeroed by bound blk 0

// ---------------------------------------------------------------------------
// Stage 1a: boundary bitmasks. One thread per (b, word, column).
// Block 0 zeroes hist+cnts (stream order guards all consumers).
// ---------------------------------------------------------------------------
__global__ __launch_bounds__(64) void bound_kernel(const int* __restrict__ tgt,
                                                   unsigned int* __restrict__ maskw,
                                                   unsigned int* __restrict__ zbuf) {
    int cidx = blockIdx.x * 64 + threadIdx.x;           // [b][w][j], 32768 total
    if (blockIdx.x == 0) {
        for (int k = threadIdx.x; k < NZERO; k += 64) zbuf[k] = 0u;
    }
    int j = cidx & (NW - 1);
    int w = (cidx >> 9) & (NWRD - 1);
    int b = cidx >> 13;
    const int* t = tgt + (size_t)b * NH * NW;
    unsigned int mask = 0u;
    int i0 = w * 32;
    int cur = t[(size_t)i0 * NW + j];
    for (int k = 0; k < 32; ++k) {
        int i = i0 + k;
        int nxt = (i + 1 < NH) ? t[(size_t)(i + 1) * NW + j] : cur;
        bool bnd = (cur == 255);
        if (i + 1 < NH && nxt != cur) bnd = true;
        if (j + 1 < NW && t[(size_t)i * NW + j + 1] != cur) bnd = true;
        if (bnd) mask |= (1u << k);
        cur = nxt;
    }
    maskw[cidx] = mask;
}

// ---------------------------------------------------------------------------
// Stage 1b+2 fused: block per row; batch mask set in LDS; nearest-set-bit ->
// G^2 -> row min-plus transform -> final dist.
// ---------------------------------------------------------------------------
__global__ __launch_bounds__(512) void vdistrow_kernel(const unsigned int* __restrict__ maskw,
                                                       float* __restrict__ dist) {
    __shared__ unsigned int smw[NWRD][NW];   // 32 KB: all masks of this batch
    __shared__ float s[NW];
    __shared__ unsigned int anyw[8];
    const int tid = threadIdx.x;             // = column j
    const int row = blockIdx.x;              // b*NH + i
    const int b = row >> 9;
    const int i = row & (NH - 1);
    const unsigned int* mcol = maskw + (size_t)b * NWRD * NW;
    unsigned int acc = 0u;
#pragma unroll
    for (int w = 0; w < NWRD; ++w) {
        unsigned int v = mcol[w * NW + tid];
        smw[w][tid] = v;
        acc |= v;
    }
    unsigned long long bal = __ballot(acc != 0u);
    if ((tid & 63) == 0) anyw[tid >> 6] = (bal != 0ull) ? 1u : 0u;

    const int wi = i >> 5, bi = i & 31;
    int down = 1 << 20;
    unsigned int m = smw[wi][tid] & ((2u << bi) - 1u);   // bits 0..bi
    if (m) down = bi - (31 - __clz(m));
    else {
        for (int w = wi - 1; w >= 0; --w) {
            unsigned int mm = smw[w][tid];
            if (mm) { down = bi + 32 * (wi - w) - (31 - __clz(mm)); break; }
        }
    }
    int up = 1 << 20;
    unsigned int mu = smw[wi][tid] & ~((1u << bi) - 1u); // bits bi..31
    if (mu) up = (__ffs(mu) - 1) - bi;
    else {
        for (int w = wi + 1; w < NWRD; ++w) {
            unsigned int mm = smw[w][tid];
            if (mm) { up = 32 * (w - wi) + (__ffs(mm) - 1) - bi; break; }
        }
    }
    int gi = min(down, up);
    float G = (gi >= (1 << 20)) ? INF6 : (float)gi;
    s[tid] = G * G;
    __syncthreads();
    bool has = (anyw[0] | anyw[1] | anyw[2] | anyw[3] |
                anyw[4] | anyw[5] | anyw[6] | anyw[7]) != 0u;
    float best = s[tid];
    for (int r = 1; r < NW; ++r) {
        float rr = (float)(r * r);
        if (rr >= best) break;
        int jl = tid - r, jr = tid + r;
        if (jl >= 0) best = fminf(best, s[jl] + rr);
        if (jr < NW) best = fminf(best, s[jr] + rr);
    }
    dist[(size_t)row * NW + tid] = has ? fmaxf(sqrtf(best) - 1.f, 0.f) : 0.f;
}

// ---------------------------------------------------------------------------
// Stage 3 fused: LSE + kl map + 8-replica histogram. Block = 4 rows x full
// width, 512 threads. Phase 1: 5x512 LSE tile in LDS (25% dup across blocks;
// rows 0..3 also written to lsem for dirce). Phase 2: per-row kl from direct
// (cached) logit loads + LDS LSEs; fused histogram.
// ---------------------------------------------------------------------------
__global__ __launch_bounds__(512) void klse_kernel(const float* __restrict__ logits,
                                                   float* __restrict__ lsem,
                                                   float* __restrict__ klb,
                                                   unsigned int* __restrict__ hist) {
    __shared__ float lseL[R4 + 1][NW];          // 10 KB
    __shared__ float lad[NLAD];
    __shared__ unsigned int lh[NLAD + 1];
    const int tid = threadIdx.x;                // = column j
    const int bid = blockIdx.x;
    const int b = bid >> 7;                     // NH/R4 = 128 blocks per batch
    const int i0 = (bid & 127) * R4;
    if (tid == 0) {
        float e = 1e-5f;
        for (int k = 0; k < NLAD; ++k) { lad[k] = e; e *= 1.2f; }
    }
    if (tid < NLAD + 1) lh[tid] = 0u;

    // phase 1: LSEs for rows i0..i0+4 (halo row R4 skipped at batch bottom)
    for (int r = 0; r <= R4; ++r) {
        const int i = i0 + r;
        if (i < NH) {
            const size_t pix = (size_t)(b * NH + i) * NW + tid;
            const float* v = logits + pix * NC;
            float mx = v[0];
#pragma unroll
            for (int c = 1; c < NC; ++c) mx = fmaxf(mx, v[c]);
            float se = 0.f;
#pragma unroll
            for (int c = 0; c < NC; ++c) se += expf(v[c] - mx);
            float L = mx + logf(se);
            lseL[r][tid] = L;
            if (r < R4) lsem[pix] = L;
        }
    }
    __syncthreads();

    // phase 2: kl for rows i0..i0+3
    const bool hasr = (tid < NW - 1);
    for (int r = 0; r < R4; ++r) {
        const int i = i0 + r;
        const size_t pix = (size_t)(b * NH + i) * NW + tid;
        const bool hasd = (i < NH - 1);
        const float lse_c = lseL[r][tid];
        const float lse_r = hasr ? lseL[r][tid + 1] : 0.f;
        const float lse_d = hasd ? lseL[r + 1][tid] : 0.f;

        const float* lcp = logits + pix * NC;
        float lc[NC], lr[NC], ld[NC];
#pragma unroll
        for (int c = 0; c < NC; ++c) lc[c] = lcp[c];
        if (hasr) {
#pragma unroll
            for (int c = 0; c < NC; ++c) lr[c] = lcp[NC + c];
        } else {
#pragma unroll
            for (int c = 0; c < NC; ++c) lr[c] = 0.f;
        }
        if (hasd) {
            const float* ldp = lcp + (size_t)NW * NC;
#pragma unroll
            for (int c = 0; c < NC; ++c) ld[c] = ldp[c];
        } else {
#pragma unroll
            for (int c = 0; c < NC; ++c) ld[c] = 0.f;
        }

        float negH = 0.f, dotr = 0.f, dotd = 0.f;
#pragma unroll
        for (int c = 0; c < NC; ++c) {
            float s = lc[c] - lse_c;
            float p = expf(s);
            negH += p * s;
            dotr += p * lr[c];
            dotd += p * ld[c];
        }
        float kl = 0.f;
        if (hasd) kl += negH + lse_d - dotd;
        if (hasr) kl += negH + lse_r - dotr;
        klb[pix] = kl;

        int lo = 0, hi = NLAD;
        while (lo < hi) { int mid = (lo + hi) >> 1; if (kl > lad[mid]) lo = mid + 1; else hi = mid; }
        atomicAdd(&lh[lo], 1u);
    }
    __syncthreads();
    if (tid < NLAD + 1 && lh[tid])
        atomicAdd(&hist[(bid & (NREP - 1)) * HSTRIDE + tid], lh[tid]);
}

// ---------------------------------------------------------------------------
// Stage 6a: eps (per-block from replica histogram) + validity + compaction.
// ---------------------------------------------------------------------------
__global__ __launch_bounds__(256) void valid_kernel(const float* __restrict__ klb,
                                                    const float* __restrict__ dist,
                                                    const unsigned int* __restrict__ hist,
                                                    unsigned int* __restrict__ cnts,
                                                    unsigned int* __restrict__ list) {
    __shared__ unsigned int tot[NLAD + 1];
    __shared__ float epsS;
    const int tid = threadIdx.x;
    if (tid < NLAD + 1) {
        unsigned int s = 0;
        for (int r = 0; r < NREP; ++r) s += hist[r * HSTRIDE + tid];
        tot[tid] = s;
    }
    __syncthreads();
    if (tid == 0) {
        float lad[NLAD];
        float e = 1e-5f;
        for (int q = 0; q < NLAD; ++q) { lad[q] = e; e *= 1.2f; }
        unsigned int suf = 0u;
        int K = NLAD - 1;
        // find first K with count(kl > lad[K]) = suffix(K+1) <= 2621.44
        unsigned int sufs[NLAD + 2];
        sufs[NLAD + 1] = 0u;
        for (int q = NLAD; q >= 0; --q) sufs[q] = sufs[q + 1] + tot[q];
        K = 0;
        while (K < NLAD - 1 && (float)sufs[K + 1] > 2621.44f) K++;
        epsS = lad[K];
        (void)suf;
    }
    __syncthreads();
    const float eps = epsS;

    const int b = blockIdx.z;
    const int i = blockIdx.y * TS + (tid >> 4);
    const int j = blockIdx.x * TS + (tid & 15);
    const float* klp = klb + (size_t)b * NH * NW;
    const float* dp = dist + (size_t)b * NH * NW;

    bool pb = false;
    for (int di = -1; di <= 1; ++di) {
        int ii = i + di; if (ii < 0 || ii >= NH) continue;
        for (int dj = -1; dj <= 1; ++dj) {
            int jj = j + dj; if (jj < 0 || jj >= NW) continue;
            if (klp[(size_t)ii * NW + jj] > eps) pb = true;
        }
    }

    const int dxs[9] = {1, -1, 0, 0, -1, 1, -1, 1, 0};
    const int dys[9] = {0, 0, -1, 1, 1, 1, -1, -1, 0};
    float best = MAXDIS; int gidx = 0;
#pragma unroll
    for (int k = 0; k < 9; ++k) {
        int ii = i + dxs[k], jj = j + dys[k];
        float v = (ii >= 0 && ii < NH && jj >= 0 && jj < NW) ? dp[(size_t)ii * NW + jj] : MAXDIS;
        if (k == 0) { best = v; gidx = 0; }
        else if (v < best) { best = v; gidx = k; }
    }
    bool valid = pb && (gidx != 8);

    const int pix = (b * NH + i) * NW + j;
    const int lane = tid & 63;
    unsigned long long mk = __ballot(valid);
    int cnt = __popcll(mk);
    int flatw = (((blockIdx.z * gridDim.y + blockIdx.y) * gridDim.x + blockIdx.x) << 2) | (tid >> 6);
    int seg = flatw & (NSEG - 1);
    unsigned int base = 0u;
    if (lane == 0 && cnt) base = atomicAdd(&cnts[seg], (unsigned int)cnt);
    base = (unsigned int)__shfl((int)base, 0, 64);
    if (valid) {
        unsigned int off = base + (unsigned int)__popcll(mk & ((1ull << lane) - 1ull));
        if (off < SEGCAP)
            list[seg * SEGCAP + off] = (unsigned int)pix | ((unsigned int)gidx << 20);
    }
}

// ---------------------------------------------------------------------------
// Stage 6b: CE over valid pixels. 8 lanes per pixel; every (seg,slot) gets
// written (0 when unused) -> no pre-zeroing, compact deterministic-order sum.
// ---------------------------------------------------------------------------
__global__ __launch_bounds__(256) void dirce_kernel(const float* __restrict__ logits,
                                                    const float* __restrict__ lsem,
                                                    const float* __restrict__ dist,
                                                    const unsigned int* __restrict__ cnts,
                                                    const unsigned int* __restrict__ list,
                                                    float* __restrict__ ceval) {
    const int t = blockIdx.x * 256 + threadIdx.x;
    const int e = t >> 3;                       // entry slot
    const int d = t & 7;                        // neighbor lane
    const int s = e >> 9;                       // segment (SEGCAP=512)
    const int k = e & (SEGCAP - 1);
    unsigned int cs = cnts[s];
    if ((unsigned int)k >= min(cs, (unsigned int)SEGCAP)) {
        if (d == 0) ceval[e] = 0.f;
        return;
    }
    unsigned int w = list[s * SEGCAP + k];
    const int pix = (int)(w & (NPIX - 1));
    const int gidx = (int)(w >> 20);
    const int j = pix & (NW - 1);
    const int i = (pix >> 9) & (NH - 1);

    const unsigned int DXP = (2u<<0)|(0u<<2)|(1u<<4)|(1u<<6)|(0u<<8)|(2u<<10)|(0u<<12)|(2u<<14);
    const unsigned int DYP = (1u<<0)|(1u<<2)|(0u<<4)|(2u<<6)|(2u<<8)|(2u<<10)|(0u<<12)|(0u<<14);
    const int dx = (int)((DXP >> (2 * d)) & 3u) - 1;
    const int dy = (int)((DYP >> (2 * d)) & 3u) - 1;
    const int ii = i + dx, jj = j + dy;
    const bool inb = (ii >= 0 && ii < NH && jj >= 0 && jj < NW);

    const float lse_c = lsem[pix];
    const float* lcp = logits + (size_t)pix * NC;
    float lc[NC];
    float sumlc = 0.f;
#pragma unroll
    for (int c = 0; c < NC; ++c) { lc[c] = lcp[c]; sumlc += lc[c]; }

    float klm;
    if (inb) {
        const int npix = pix + dx * NW + dy;
        const float lse_n = lsem[npix];
        const float* lnp = logits + (size_t)npix * NC;
        float negH = 0.f, dot = 0.f;
#pragma unroll
        for (int c = 0; c < NC; ++c) {
            float sv = lnp[c] - lse_n;
            float p = expf(sv);
            negH += p * sv;
            dot += p * lc[c];
        }
        klm = negH + lse_c - dot;
    } else {
        klm = -logf(19.f) + lse_c - sumlc / 19.f;
    }

    float m2 = klm;
#pragma unroll
    for (int o = 4; o > 0; o >>= 1) m2 = fmaxf(m2, __shfl_xor(m2, o, 8));
    float ex = expf(klm - m2);
    float s2 = ex;
#pragma unroll
    for (int o = 4; o > 0; o >>= 1) s2 += __shfl_xor(s2, o, 8);
    float lse = m2 + logf(s2);
    float lp = klm - lse;
    float slp = lp;
#pragma unroll
    for (int o = 4; o > 0; o >>= 1) slp += __shfl_xor(slp, o, 8);
    float kg = (d == gidx) ? lp : 0.f;
#pragma unroll
    for (int o = 4; o > 0; o >>= 1) kg += __shfl_xor(kg, o, 8);

    if (d == 0) {
        float ce = -(0.2f / 8.f) * slp - 0.8f * kg;
        float wgt = fminf(dist[pix], 20.f) / 20.f;
        ceval[e] = ce * wgt;
    }
}

// ---------------------------------------------------------------------------
// Stage 7: fixed-order reduce of ceval slots + valid count -> loss.
// ---------------------------------------------------------------------------
__global__ __launch_bounds__(256) void final_kernel(const float* __restrict__ ceval,
                                                    const unsigned int* __restrict__ cnts,
                                                    float* __restrict__ out) {
    __shared__ float r[256];
    const int tid = threadIdx.x;
    float s = 0.f;
    for (int idx = tid; idx < NSEG * SEGCAP; idx += 256) s += ceval[idx];
    r[tid] = s;
    __syncthreads();
    for (int q = 128; q > 0; q >>= 1) {
        if (tid < q) r[tid] += r[tid + q];
        __syncthreads();
    }
    if (tid == 0) {
        unsigned int vf = 0;
        for (int q = 0; q < NSEG; ++q) vf += cnts[q];
        out[0] = r[0] / fmaxf((float)vf, 1.f);
    }
}

extern "C" void kernel_launch(void* const* d_in, const int* in_sizes, int n_in,
                              void* d_out, int out_size, void* d_ws, size_t ws_size,
                              hipStream_t stream) {
    const float* logits = (const float*)d_in[0];
    const int* target = (const int*)d_in[1];
    float* out = (float*)d_out;

    float* fws = (float*)d_ws;
    float* distb = fws;                         // NPIX floats
    float* klb = fws + NPIX;                    // NPIX floats
    float* lsem = fws + 2 * (size_t)NPIX;       // NPIX floats
    unsigned int* hist = (unsigned int*)(fws + 3 * (size_t)NPIX);   // NREP*HSTRIDE
    unsigned int* cnts = hist + NREP * HSTRIDE;                     // NSEG
    unsigned int* list = cnts + NSEG;                               // NSEG*SEGCAP
    float* ceval = (float*)(list + NSEG * SEGCAP);                  // NSEG*SEGCAP
    unsigned int* maskw = (unsigned int*)(ceval + NSEG * SEGCAP);   // NB*NWRD*NW

    // bound block 0 zeroes hist+cnts; stream order guards all consumers
    bound_kernel<<<NB * NWRD * NW / 64, 64, 0, stream>>>(target, maskw, hist);
    vdistrow_kernel<<<NB * NH, 512, 0, stream>>>(maskw, distb);

    klse_kernel<<<NB * NH / R4, 512, 0, stream>>>(logits, lsem, klb, hist);

    dim3 tiles(NW / TS, NH / TS, NB);
    valid_kernel<<<tiles, 256, 0, stream>>>(klb, distb, hist, cnts, list);
    dirce_kernel<<<NSEG * SEGCAP * 8 / 256, 256, 0, stream>>>(logits, lsem, distb,
                                                              cnts, list, ceval);
    final_kernel<<<1, 256, 0, stream>>>(ceval, cnts, out);
}

// Round 11
// 110.966 us; speedup vs baseline: 1.5394x; 1.5394x over previous
//
#include <hip/hip_runtime.h>
#include <math.h>

#define NB 4
#define NH 512
#define NW 512
#define NC 19
#define NPIX (NB*NH*NW)
#define TS 16
#define NLAD 128
#define INF6 1.0e6f
#define MAXDIS 1.0e5f
#define NWRD 16          // 512 rows / 32 bits
#define NREP 8           // histogram replicas
#define HSTRIDE 132      // padded per-replica stride (129 bins)
#define NSEG 128         // compaction segments
#define SEGCAP 512       // entries per segment (expected max ~250)
#define R4 4             // rows per klse block
#define NDCB (NSEG*SEGCAP*8/256)      // dirce blocks = 2048
#define NZERO (NREP*HSTRIDE + NSEG)   // hist + cnts words zeroed by bound blk 0

// ---------------------------------------------------------------------------
// Stage 1a: boundary bitmasks. One thread per (b, word, column).
// Block 0 zeroes hist+cnts (stream order guards all consumers).
// ---------------------------------------------------------------------------
__global__ __launch_bounds__(64) void bound_kernel(const int* __restrict__ tgt,
                                                   unsigned int* __restrict__ maskw,
                                                   unsigned int* __restrict__ zbuf) {
    int cidx = blockIdx.x * 64 + threadIdx.x;           // [b][w][j], 32768 total
    if (blockIdx.x == 0) {
        for (int k = threadIdx.x; k < NZERO; k += 64) zbuf[k] = 0u;
    }
    int j = cidx & (NW - 1);
    int w = (cidx >> 9) & (NWRD - 1);
    int b = cidx >> 13;
    const int* t = tgt + (size_t)b * NH * NW;
    unsigned int mask = 0u;
    int i0 = w * 32;
    int cur = t[(size_t)i0 * NW + j];
    for (int k = 0; k < 32; ++k) {
        int i = i0 + k;
        int nxt = (i + 1 < NH) ? t[(size_t)(i + 1) * NW + j] : cur;
        bool bnd = (cur == 255);
        if (i + 1 < NH && nxt != cur) bnd = true;
        if (j + 1 < NW && t[(size_t)i * NW + j + 1] != cur) bnd = true;
        if (bnd) mask |= (1u << k);
        cur = nxt;
    }
    maskw[cidx] = mask;
}

// ---------------------------------------------------------------------------
// Stage 1b+2 fused: block per row; batch mask set in LDS; nearest-set-bit ->
// G^2 -> row min-plus transform -> final dist.
// ---------------------------------------------------------------------------
__global__ __launch_bounds__(512) void vdistrow_kernel(const unsigned int* __restrict__ maskw,
                                                       float* __restrict__ dist) {
    __shared__ unsigned int smw[NWRD][NW];   // 32 KB: all masks of this batch
    __shared__ float s[NW];
    __shared__ unsigned int anyw[8];
    const int tid = threadIdx.x;             // = column j
    const int row = blockIdx.x;              // b*NH + i
    const int b = row >> 9;
    const int i = row & (NH - 1);
    const unsigned int* mcol = maskw + (size_t)b * NWRD * NW;
    unsigned int acc = 0u;
#pragma unroll
    for (int w = 0; w < NWRD; ++w) {
        unsigned int v = mcol[w * NW + tid];
        smw[w][tid] = v;
        acc |= v;
    }
    unsigned long long bal = __ballot(acc != 0u);
    if ((tid & 63) == 0) anyw[tid >> 6] = (bal != 0ull) ? 1u : 0u;

    const int wi = i >> 5, bi = i & 31;
    int down = 1 << 20;
    unsigned int m = smw[wi][tid] & ((2u << bi) - 1u);   // bits 0..bi
    if (m) down = bi - (31 - __clz(m));
    else {
        for (int w = wi - 1; w >= 0; --w) {
            unsigned int mm = smw[w][tid];
            if (mm) { down = bi + 32 * (wi - w) - (31 - __clz(mm)); break; }
        }
    }
    int up = 1 << 20;
    unsigned int mu = smw[wi][tid] & ~((1u << bi) - 1u); // bits bi..31
    if (mu) up = (__ffs(mu) - 1) - bi;
    else {
        for (int w = wi + 1; w < NWRD; ++w) {
            unsigned int mm = smw[w][tid];
            if (mm) { up = 32 * (w - wi) + (__ffs(mm) - 1) - bi; break; }
        }
    }
    int gi = min(down, up);
    float G = (gi >= (1 << 20)) ? INF6 : (float)gi;
    s[tid] = G * G;
    __syncthreads();
    bool has = (anyw[0] | anyw[1] | anyw[2] | anyw[3] |
                anyw[4] | anyw[5] | anyw[6] | anyw[7]) != 0u;
    float best = s[tid];
    for (int r = 1; r < NW; ++r) {
        float rr = (float)(r * r);
        if (rr >= best) break;
        int jl = tid - r, jr = tid + r;
        if (jl >= 0) best = fminf(best, s[jl] + rr);
        if (jr < NW) best = fminf(best, s[jr] + rr);
    }
    dist[(size_t)row * NW + tid] = has ? fmaxf(sqrtf(best) - 1.f, 0.f) : 0.f;
}

// ---------------------------------------------------------------------------
// Stage 3 fused: LSE + kl map + 8-replica histogram. Block = 4 rows x full
// width, 512 threads.
// ---------------------------------------------------------------------------
__global__ __launch_bounds__(512) void klse_kernel(const float* __restrict__ logits,
                                                   float* __restrict__ lsem,
                                                   float* __restrict__ klb,
                                                   unsigned int* __restrict__ hist) {
    __shared__ float lseL[R4 + 1][NW];          // 10 KB
    __shared__ float lad[NLAD];
    __shared__ unsigned int lh[NLAD + 1];
    const int tid = threadIdx.x;                // = column j
    const int bid = blockIdx.x;
    const int b = bid >> 7;                     // NH/R4 = 128 blocks per batch
    const int i0 = (bid & 127) * R4;
    if (tid == 0) {
        float e = 1e-5f;
        for (int k = 0; k < NLAD; ++k) { lad[k] = e; e *= 1.2f; }
    }
    if (tid < NLAD + 1) lh[tid] = 0u;

    // phase 1: LSEs for rows i0..i0+4 (halo row R4 skipped at batch bottom)
    for (int r = 0; r <= R4; ++r) {
        const int i = i0 + r;
        if (i < NH) {
            const size_t pix = (size_t)(b * NH + i) * NW + tid;
            const float* v = logits + pix * NC;
            float mx = v[0];
#pragma unroll
            for (int c = 1; c < NC; ++c) mx = fmaxf(mx, v[c]);
            float se = 0.f;
#pragma unroll
            for (int c = 0; c < NC; ++c) se += expf(v[c] - mx);
            float L = mx + logf(se);
            lseL[r][tid] = L;
            if (r < R4) lsem[pix] = L;
        }
    }
    __syncthreads();

    // phase 2: kl for rows i0..i0+3
    const bool hasr = (tid < NW - 1);
    for (int r = 0; r < R4; ++r) {
        const int i = i0 + r;
        const size_t pix = (size_t)(b * NH + i) * NW + tid;
        const bool hasd = (i < NH - 1);
        const float lse_c = lseL[r][tid];
        const float lse_r = hasr ? lseL[r][tid + 1] : 0.f;
        const float lse_d = hasd ? lseL[r + 1][tid] : 0.f;

        const float* lcp = logits + pix * NC;
        float lc[NC], lr[NC], ld[NC];
#pragma unroll
        for (int c = 0; c < NC; ++c) lc[c] = lcp[c];
        if (hasr) {
#pragma unroll
            for (int c = 0; c < NC; ++c) lr[c] = lcp[NC + c];
        } else {
#pragma unroll
            for (int c = 0; c < NC; ++c) lr[c] = 0.f;
        }
        if (hasd) {
            const float* ldp = lcp + (size_t)NW * NC;
#pragma unroll
            for (int c = 0; c < NC; ++c) ld[c] = ldp[c];
        } else {
#pragma unroll
            for (int c = 0; c < NC; ++c) ld[c] = 0.f;
        }

        float negH = 0.f, dotr = 0.f, dotd = 0.f;
#pragma unroll
        for (int c = 0; c < NC; ++c) {
            float s = lc[c] - lse_c;
            float p = expf(s);
            negH += p * s;
            dotr += p * lr[c];
            dotd += p * ld[c];
        }
        float kl = 0.f;
        if (hasd) kl += negH + lse_d - dotd;
        if (hasr) kl += negH + lse_r - dotr;
        klb[pix] = kl;

        int lo = 0, hi = NLAD;
        while (lo < hi) { int mid = (lo + hi) >> 1; if (kl > lad[mid]) lo = mid + 1; else hi = mid; }
        atomicAdd(&lh[lo], 1u);
    }
    __syncthreads();
    if (tid < NLAD + 1 && lh[tid])
        atomicAdd(&hist[(bid & (NREP - 1)) * HSTRIDE + tid], lh[tid]);
}

// ---------------------------------------------------------------------------
// Stage 6a: eps (per-block from replica histogram) + validity + compaction.
// ---------------------------------------------------------------------------
__global__ __launch_bounds__(256) void valid_kernel(const float* __restrict__ klb,
                                                    const float* __restrict__ dist,
                                                    const unsigned int* __restrict__ hist,
                                                    unsigned int* __restrict__ cnts,
                                                    unsigned int* __restrict__ list) {
    __shared__ unsigned int tot[NLAD + 1];
    __shared__ float epsS;
    const int tid = threadIdx.x;
    if (tid < NLAD + 1) {
        unsigned int s = 0;
        for (int r = 0; r < NREP; ++r) s += hist[r * HSTRIDE + tid];
        tot[tid] = s;
    }
    __syncthreads();
    if (tid == 0) {
        float lad[NLAD];
        float e = 1e-5f;
        for (int q = 0; q < NLAD; ++q) { lad[q] = e; e *= 1.2f; }
        unsigned int sufs[NLAD + 2];
        sufs[NLAD + 1] = 0u;
        for (int q = NLAD; q >= 0; --q) sufs[q] = sufs[q + 1] + tot[q];
        int K = 0;
        while (K < NLAD - 1 && (float)sufs[K + 1] > 2621.44f) K++;
        epsS = lad[K];
    }
    __syncthreads();
    const float eps = epsS;

    const int b = blockIdx.z;
    const int i = blockIdx.y * TS + (tid >> 4);
    const int j = blockIdx.x * TS + (tid & 15);
    const float* klp = klb + (size_t)b * NH * NW;
    const float* dp = dist + (size_t)b * NH * NW;

    bool pb = false;
    for (int di = -1; di <= 1; ++di) {
        int ii = i + di; if (ii < 0 || ii >= NH) continue;
        for (int dj = -1; dj <= 1; ++dj) {
            int jj = j + dj; if (jj < 0 || jj >= NW) continue;
            if (klp[(size_t)ii * NW + jj] > eps) pb = true;
        }
    }

    const int dxs[9] = {1, -1, 0, 0, -1, 1, -1, 1, 0};
    const int dys[9] = {0, 0, -1, 1, 1, 1, -1, -1, 0};
    float best = MAXDIS; int gidx = 0;
#pragma unroll
    for (int k = 0; k < 9; ++k) {
        int ii = i + dxs[k], jj = j + dys[k];
        float v = (ii >= 0 && ii < NH && jj >= 0 && jj < NW) ? dp[(size_t)ii * NW + jj] : MAXDIS;
        if (k == 0) { best = v; gidx = 0; }
        else if (v < best) { best = v; gidx = k; }
    }
    bool valid = pb && (gidx != 8);

    const int pix = (b * NH + i) * NW + j;
    const int lane = tid & 63;
    unsigned long long mk = __ballot(valid);
    int cnt = __popcll(mk);
    int flatw = (((blockIdx.z * gridDim.y + blockIdx.y) * gridDim.x + blockIdx.x) << 2) | (tid >> 6);
    int seg = flatw & (NSEG - 1);
    unsigned int base = 0u;
    if (lane == 0 && cnt) base = atomicAdd(&cnts[seg], (unsigned int)cnt);
    base = (unsigned int)__shfl((int)base, 0, 64);
    if (valid) {
        unsigned int off = base + (unsigned int)__popcll(mk & ((1ull << lane) - 1ull));
        if (off < SEGCAP)
            list[seg * SEGCAP + off] = (unsigned int)pix | ((unsigned int)gidx << 20);
    }
}

// ---------------------------------------------------------------------------
// Stage 6b: CE over valid pixels, 8 lanes per pixel, PLUS in-block LDS tree
// reduce -> one partial per block (2048 total). No dense ceval buffer.
// ---------------------------------------------------------------------------
__global__ __launch_bounds__(256) void dirce_kernel(const float* __restrict__ logits,
                                                    const float* __restrict__ lsem,
                                                    const float* __restrict__ dist,
                                                    const unsigned int* __restrict__ cnts,
                                                    const unsigned int* __restrict__ list,
                                                    float* __restrict__ partials) {
    __shared__ float rs[256];
    const int tid = threadIdx.x;
    const int t = blockIdx.x * 256 + tid;
    const int e = t >> 3;                       // entry slot
    const int d = t & 7;                        // neighbor lane
    const int s = e >> 9;                       // segment (SEGCAP=512)
    const int k = e & (SEGCAP - 1);
    unsigned int cs = cnts[s];
    float myce = 0.f;
    if ((unsigned int)k < min(cs, (unsigned int)SEGCAP)) {
        unsigned int w = list[s * SEGCAP + k];
        const int pix = (int)(w & (NPIX - 1));
        const int gidx = (int)(w >> 20);
        const int j = pix & (NW - 1);
        const int i = (pix >> 9) & (NH - 1);

        const unsigned int DXP = (2u<<0)|(0u<<2)|(1u<<4)|(1u<<6)|(0u<<8)|(2u<<10)|(0u<<12)|(2u<<14);
        const unsigned int DYP = (1u<<0)|(1u<<2)|(0u<<4)|(2u<<6)|(2u<<8)|(2u<<10)|(0u<<12)|(0u<<14);
        const int dx = (int)((DXP >> (2 * d)) & 3u) - 1;
        const int dy = (int)((DYP >> (2 * d)) & 3u) - 1;
        const int ii = i + dx, jj = j + dy;
        const bool inb = (ii >= 0 && ii < NH && jj >= 0 && jj < NW);

        const float lse_c = lsem[pix];
        const float* lcp = logits + (size_t)pix * NC;
        float lc[NC];
        float sumlc = 0.f;
#pragma unroll
        for (int c = 0; c < NC; ++c) { lc[c] = lcp[c]; sumlc += lc[c]; }

        float klm;
        if (inb) {
            const int npix = pix + dx * NW + dy;
            const float lse_n = lsem[npix];
            const float* lnp = logits + (size_t)npix * NC;
            float negH = 0.f, dot = 0.f;
#pragma unroll
            for (int c = 0; c < NC; ++c) {
                float sv = lnp[c] - lse_n;
                float p = expf(sv);
                negH += p * sv;
                dot += p * lc[c];
            }
            klm = negH + lse_c - dot;
        } else {
            klm = -logf(19.f) + lse_c - sumlc / 19.f;
        }

        float m2 = klm;
#pragma unroll
        for (int o = 4; o > 0; o >>= 1) m2 = fmaxf(m2, __shfl_xor(m2, o, 8));
        float ex = expf(klm - m2);
        float s2 = ex;
#pragma unroll
        for (int o = 4; o > 0; o >>= 1) s2 += __shfl_xor(s2, o, 8);
        float lse = m2 + logf(s2);
        float lp = klm - lse;
        float slp = lp;
#pragma unroll
        for (int o = 4; o > 0; o >>= 1) slp += __shfl_xor(slp, o, 8);
        float kg = (d == gidx) ? lp : 0.f;
#pragma unroll
        for (int o = 4; o > 0; o >>= 1) kg += __shfl_xor(kg, o, 8);

        if (d == 0) {
            float ce = -(0.2f / 8.f) * slp - 0.8f * kg;
            float wgt = fminf(dist[pix], 20.f) / 20.f;
            myce = ce * wgt;
        }
    }
    rs[tid] = myce;
    __syncthreads();
    for (int q = 128; q > 0; q >>= 1) {
        if (tid < q) rs[tid] += rs[tid + q];
        __syncthreads();
    }
    if (tid == 0) partials[blockIdx.x] = rs[0];
}

// ---------------------------------------------------------------------------
// Stage 7: reduce 2048 block partials + valid count -> loss.
// ---------------------------------------------------------------------------
__global__ __launch_bounds__(256) void final_kernel(const float* __restrict__ partials,
                                                    const unsigned int* __restrict__ cnts,
                                                    float* __restrict__ out) {
    __shared__ float r[256];
    const int tid = threadIdx.x;
    float s = 0.f;
#pragma unroll
    for (int q = 0; q < NDCB / 256; ++q) s += partials[tid + q * 256];
    r[tid] = s;
    __syncthreads();
    for (int q = 128; q > 0; q >>= 1) {
        if (tid < q) r[tid] += r[tid + q];
        __syncthreads();
    }
    if (tid == 0) {
        unsigned int vf = 0;
        for (int q = 0; q < NSEG; ++q) vf += cnts[q];
        out[0] = r[0] / fmaxf((float)vf, 1.f);
    }
}

extern "C" void kernel_launch(void* const* d_in, const int* in_sizes, int n_in,
                              void* d_out, int out_size, void* d_ws, size_t ws_size,
                              hipStream_t stream) {
    const float* logits = (const float*)d_in[0];
    const int* target = (const int*)d_in[1];
    float* out = (float*)d_out;

    float* fws = (float*)d_ws;
    float* distb = fws;                         // NPIX floats
    float* klb = fws + NPIX;                    // NPIX floats
    float* lsem = fws + 2 * (size_t)NPIX;       // NPIX floats
    unsigned int* hist = (unsigned int*)(fws + 3 * (size_t)NPIX);   // NREP*HSTRIDE
    unsigned int* cnts = hist + NREP * HSTRIDE;                     // NSEG
    unsigned int* list = cnts + NSEG;                               // NSEG*SEGCAP
    float* partials = (float*)(list + NSEG * SEGCAP);               // NDCB
    unsigned int* maskw = (unsigned int*)(partials + NDCB);         // NB*NWRD*NW

    // bound block 0 zeroes hist+cnts; stream order guards all consumers
    bound_kernel<<<NB * NWRD * NW / 64, 64, 0, stream>>>(target, maskw, hist);
    vdistrow_kernel<<<NB * NH, 512, 0, stream>>>(maskw, distb);

    klse_kernel<<<NB * NH / R4, 512, 0, stream>>>(logits, lsem, klb, hist);

    dim3 tiles(NW / TS, NH / TS, NB);
    valid_kernel<<<tiles, 256, 0, stream>>>(klb, distb, hist, cnts, list);
    dirce_kernel<<<NDCB, 256, 0, stream>>>(logits, lsem, distb, cnts, list, partials);
    final_kernel<<<1, 256, 0, stream>>>(partials, cnts, out);
}